// Round 2
// baseline (1838.414 us; speedup 1.0000x reference)
//
#include <hip/hip_runtime.h>
#include <hip/hip_bf16.h>
#include <math.h>

#define DIM    512
#define HEADS  8
#define DHEAD  64
#define BATCH  4
#define NQ     2048
#define NKV    1024
#define ATT_SCALE 0.125f   // 64^-0.5
#define LN_EPS 1e-5f

// ---------------------------------------------------------------------------
// LayerNorm: one block (128 threads) per 512-float row; float4 per thread.
// ---------------------------------------------------------------------------
__global__ __launch_bounds__(128)
void ln_kernel(const float* __restrict__ x, const float* __restrict__ g,
               const float* __restrict__ b, float* __restrict__ out)
{
    __shared__ float red[4];
    const int row = blockIdx.x;
    const int t = threadIdx.x;
    const int wid = t >> 6, lane = t & 63;

    float4 v = *(const float4*)&x[(size_t)row * DIM + t * 4];
    float s  = v.x + v.y + v.z + v.w;
    float sq = v.x*v.x + v.y*v.y + v.z*v.z + v.w*v.w;
#pragma unroll
    for (int off = 32; off >= 1; off >>= 1) {
        s  += __shfl_xor(s, off);
        sq += __shfl_xor(sq, off);
    }
    if (lane == 0) { red[wid] = s; red[2 + wid] = sq; }
    __syncthreads();
    s = red[0] + red[1]; sq = red[2] + red[3];

    const float mu = s * (1.0f / DIM);
    const float rs = rsqrtf(sq * (1.0f / DIM) - mu * mu + LN_EPS);
    float4 gv = *(const float4*)&g[t * 4];
    float4 bv = *(const float4*)&b[t * 4];
    float4 o;
    o.x = (v.x - mu) * rs * gv.x + bv.x;
    o.y = (v.y - mu) * rs * gv.y + bv.y;
    o.z = (v.z - mu) * rs * gv.z + bv.z;
    o.w = (v.w - mu) * rs * gv.w + bv.w;
    *(float4*)&out[(size_t)row * DIM + t * 4] = o;
}

// Double LayerNorm: out = LN(LN(x, g1,b1), g2,b2) — row stays in registers.
__global__ __launch_bounds__(128)
void ln2_kernel(const float* __restrict__ x,
                const float* __restrict__ g1, const float* __restrict__ b1,
                const float* __restrict__ g2, const float* __restrict__ b2,
                float* __restrict__ out)
{
    __shared__ float red[4];
    const int row = blockIdx.x;
    const int t = threadIdx.x;
    const int wid = t >> 6, lane = t & 63;

    float4 v = *(const float4*)&x[(size_t)row * DIM + t * 4];
    float s  = v.x + v.y + v.z + v.w;
    float sq = v.x*v.x + v.y*v.y + v.z*v.z + v.w*v.w;
#pragma unroll
    for (int off = 32; off >= 1; off >>= 1) {
        s  += __shfl_xor(s, off);
        sq += __shfl_xor(sq, off);
    }
    if (lane == 0) { red[wid] = s; red[2 + wid] = sq; }
    __syncthreads();
    s = red[0] + red[1]; sq = red[2] + red[3];
    float mu = s * (1.0f / DIM);
    float rs = rsqrtf(sq * (1.0f / DIM) - mu * mu + LN_EPS);

    float4 g = *(const float4*)&g1[t * 4];
    float4 bb = *(const float4*)&b1[t * 4];
    float4 z;
    z.x = (v.x - mu) * rs * g.x + bb.x;
    z.y = (v.y - mu) * rs * g.y + bb.y;
    z.z = (v.z - mu) * rs * g.z + bb.z;
    z.w = (v.w - mu) * rs * g.w + bb.w;

    // second LN over z
    s  = z.x + z.y + z.z + z.w;
    sq = z.x*z.x + z.y*z.y + z.z*z.z + z.w*z.w;
#pragma unroll
    for (int off = 32; off >= 1; off >>= 1) {
        s  += __shfl_xor(s, off);
        sq += __shfl_xor(sq, off);
    }
    __syncthreads();   // previous reads of red[] done
    if (lane == 0) { red[wid] = s; red[2 + wid] = sq; }
    __syncthreads();
    s = red[0] + red[1]; sq = red[2] + red[3];
    mu = s * (1.0f / DIM);
    rs = rsqrtf(sq * (1.0f / DIM) - mu * mu + LN_EPS);

    g  = *(const float4*)&g2[t * 4];
    bb = *(const float4*)&b2[t * 4];
    float4 o;
    o.x = (z.x - mu) * rs * g.x + bb.x;
    o.y = (z.y - mu) * rs * g.y + bb.y;
    o.z = (z.z - mu) * rs * g.z + bb.z;
    o.w = (z.w - mu) * rs * g.w + bb.w;
    *(float4*)&out[(size_t)row * DIM + t * 4] = o;
}

// ---------------------------------------------------------------------------
// fp32 GEMM: C[M][Nc] = A[M][K] @ W[K][Nc]  (+bias) (+gelu) (+residual)
// BM=128, BN in {64,128}, BK=16, 256 threads.
// Micro-tile: rows {ty*4..+3, 64+ty*4..+3}, cols {tx*4..+3 (, 64+tx*4..+3)}
//   -> 8x4 (BN=64) or 8x8 (BN=128) accumulators per thread.
// Register prefetch: global->reg for tile kt+1 issued before compute of kt.
// EPI: 0=none, 2=bias+residual, 3=bias+gelu
// ---------------------------------------------------------------------------
__device__ __forceinline__ float gelu_f(float x) {
    return 0.5f * x * (1.0f + erff(x * 0.70710678118654752440f));
}

template<int EPI, int BN>
__global__ __launch_bounds__(256)
void gemm_kernel(const float* __restrict__ A, const float* __restrict__ W,
                 const float* __restrict__ bias, const float* __restrict__ res,
                 float* __restrict__ C, int M, int K, int Nc)
{
    constexpr int BM = 128, BK = 16;
    constexpr int NB = BN / 64;                 // 1 or 2 column blocks
    __shared__ float As[BK][BM + 4];            // transposed: As[k][m]
    __shared__ float Bs[BK][BN + 4];            // Bs[k][n]

    const int t  = threadIdx.x;
    const int tx = t & 15;
    const int ty = t >> 4;
    const int row0 = blockIdx.y * BM;
    const int col0 = blockIdx.x * BN;

    float acc[8][4 * NB] = {};
    float4 pa[2], pb[NB];

    const float* Arow = A + (size_t)row0 * K;

#define LOAD_A(kt)                                                          \
    {                                                                       \
        _Pragma("unroll")                                                   \
        for (int i = 0; i < 2; ++i) {                                       \
            int idx = i * 256 + t, r = idx >> 2, c4 = idx & 3;              \
            pa[i] = *(const float4*)&Arow[(size_t)r * K + (kt) * BK + c4*4];\
        }                                                                   \
    }
#define LOAD_B(kt)                                                          \
    {                                                                       \
        if (NB == 2) {                                                      \
            _Pragma("unroll")                                               \
            for (int i = 0; i < 2; ++i) {                                   \
                int idx = i * 256 + t, r = idx >> 5, c4 = idx & 31;         \
                pb[i] = *(const float4*)&W[(size_t)((kt)*BK + r) * Nc +     \
                                           col0 + c4 * 4];                  \
            }                                                               \
        } else {                                                            \
            int r = t >> 4, c4 = t & 15;                                    \
            pb[0] = *(const float4*)&W[(size_t)((kt)*BK + r) * Nc +         \
                                       col0 + c4 * 4];                      \
        }                                                                   \
    }

    LOAD_A(0); LOAD_B(0);
    const int nkt = K / BK;

    for (int kt = 0; kt < nkt; ++kt) {
        __syncthreads();     // previous compute done reading LDS
#pragma unroll
        for (int i = 0; i < 2; ++i) {
            int idx = i * 256 + t, r = idx >> 2, c4 = idx & 3;
            As[c4 * 4 + 0][r] = pa[i].x;
            As[c4 * 4 + 1][r] = pa[i].y;
            As[c4 * 4 + 2][r] = pa[i].z;
            As[c4 * 4 + 3][r] = pa[i].w;
        }
        if (NB == 2) {
#pragma unroll
            for (int i = 0; i < 2; ++i) {
                int idx = i * 256 + t, r = idx >> 5, c4 = idx & 31;
                *(float4*)&Bs[r][c4 * 4] = pb[i];
            }
        } else {
            int r = t >> 4, c4 = t & 15;
            *(float4*)&Bs[r][c4 * 4] = pb[0];
        }
        __syncthreads();

        if (kt + 1 < nkt) { LOAD_A(kt + 1); LOAD_B(kt + 1); }

#pragma unroll
        for (int k = 0; k < BK; ++k) {
            float a[8], b[4 * NB];
            float4 a0 = *(const float4*)&As[k][ty * 4];
            float4 a1 = *(const float4*)&As[k][64 + ty * 4];
            a[0]=a0.x; a[1]=a0.y; a[2]=a0.z; a[3]=a0.w;
            a[4]=a1.x; a[5]=a1.y; a[6]=a1.z; a[7]=a1.w;
            float4 b0 = *(const float4*)&Bs[k][tx * 4];
            b[0]=b0.x; b[1]=b0.y; b[2]=b0.z; b[3]=b0.w;
            if (NB == 2) {
                float4 b1 = *(const float4*)&Bs[k][64 + tx * 4];
                b[4]=b1.x; b[5]=b1.y; b[6]=b1.z; b[7]=b1.w;
            }
#pragma unroll
            for (int i = 0; i < 8; ++i)
#pragma unroll
                for (int j = 0; j < 4 * NB; ++j)
                    acc[i][j] = fmaf(a[i], b[j], acc[i][j]);
        }
    }

#pragma unroll
    for (int ri = 0; ri < 2; ++ri) {
#pragma unroll
        for (int i = 0; i < 4; ++i) {
            const size_t r = (size_t)(row0 + ri * 64 + ty * 4 + i);
#pragma unroll
            for (int nb = 0; nb < NB; ++nb) {
                const int col = col0 + nb * 64 + tx * 4;
                float4 c = { acc[ri*4+i][nb*4+0], acc[ri*4+i][nb*4+1],
                             acc[ri*4+i][nb*4+2], acc[ri*4+i][nb*4+3] };
                if (EPI >= 1) {
                    float4 bv = *(const float4*)&bias[col];
                    c.x += bv.x; c.y += bv.y; c.z += bv.z; c.w += bv.w;
                }
                if (EPI == 3) {
                    c.x = gelu_f(c.x); c.y = gelu_f(c.y);
                    c.z = gelu_f(c.z); c.w = gelu_f(c.w);
                }
                if (EPI == 2) {
                    float4 rv = *(const float4*)&res[r * Nc + col];
                    c.x += rv.x; c.y += rv.y; c.z += rv.z; c.w += rv.w;
                }
                *(float4*)&C[r * Nc + col] = c;
            }
        }
    }
#undef LOAD_A
#undef LOAD_B
}

// ---------------------------------------------------------------------------
// Flash attention (fp32): one block per (64 q-rows, b*H+h). 256 threads.
// K stored transposed in LDS; P buffer aliases the K^T buffer (extra barrier).
// Q/K/V indexed with row strides so qkv / q2 / kv buffers are read in place.
// ---------------------------------------------------------------------------
__global__ __launch_bounds__(256)
void attn_kernel(const float* __restrict__ Q, int q_stride,
                 const float* __restrict__ K, const float* __restrict__ V,
                 int kv_stride, float* __restrict__ O, int n_q, int n_k)
{
    __shared__ float Qs[64][68];
    __shared__ float Vs[64][64];
    __shared__ float kps[64 * 68];               // aliased: Kt[64][68] / Ps[64][65]
    float (*Kt)[68] = (float(*)[68])kps;
    float (*Ps)[65] = (float(*)[65])kps;

    const int t  = threadIdx.x;
    const int tx = t & 15, ty = t >> 4;
    const int bh = blockIdx.y;
    const int b  = bh >> 3, h = bh & 7;
    const int q0 = blockIdx.x * 64;

    const float* Qbase = Q + (size_t)b * n_q * q_stride + h * DHEAD;
    const float* Kbase = K + (size_t)b * n_k * kv_stride + h * DHEAD;
    const float* Vbase = V + (size_t)b * n_k * kv_stride + h * DHEAD;

#pragma unroll
    for (int i = 0; i < 4; ++i) {
        int idx = i * 256 + t;
        int r = idx >> 4, c4 = idx & 15;
        *(float4*)&Qs[r][c4 * 4] =
            *(const float4*)&Qbase[(size_t)(q0 + r) * q_stride + c4 * 4];
    }

    float m_i[4], l_i[4], o_acc[4][4];
#pragma unroll
    for (int i = 0; i < 4; ++i) {
        m_i[i] = -1e30f; l_i[i] = 0.0f;
#pragma unroll
        for (int j = 0; j < 4; ++j) o_acc[i][j] = 0.0f;
    }

    const int ntiles = n_k >> 6;
    for (int it = 0; it < ntiles; ++it) {
        __syncthreads();   // previous tile fully consumed
#pragma unroll
        for (int i = 0; i < 4; ++i) {
            int idx = i * 256 + t;
            int r = idx >> 4, c4 = idx & 15;
            float4 kv4 = *(const float4*)&Kbase[(size_t)(it * 64 + r) * kv_stride + c4 * 4];
            Kt[c4 * 4 + 0][r] = kv4.x;
            Kt[c4 * 4 + 1][r] = kv4.y;
            Kt[c4 * 4 + 2][r] = kv4.z;
            Kt[c4 * 4 + 3][r] = kv4.w;
            *(float4*)&Vs[r][c4 * 4] =
                *(const float4*)&Vbase[(size_t)(it * 64 + r) * kv_stride + c4 * 4];
        }
        __syncthreads();

        // S = Q @ K^T for rows ty*4..+3, cols tx*4..+3
        float s[4][4] = {};
#pragma unroll 8
        for (int d = 0; d < DHEAD; ++d) {
            float4 kd = *(const float4*)&Kt[d][tx * 4];
            float q0v = Qs[ty * 4 + 0][d];
            float q1v = Qs[ty * 4 + 1][d];
            float q2v = Qs[ty * 4 + 2][d];
            float q3v = Qs[ty * 4 + 3][d];
            s[0][0] = fmaf(q0v, kd.x, s[0][0]); s[0][1] = fmaf(q0v, kd.y, s[0][1]);
            s[0][2] = fmaf(q0v, kd.z, s[0][2]); s[0][3] = fmaf(q0v, kd.w, s[0][3]);
            s[1][0] = fmaf(q1v, kd.x, s[1][0]); s[1][1] = fmaf(q1v, kd.y, s[1][1]);
            s[1][2] = fmaf(q1v, kd.z, s[1][2]); s[1][3] = fmaf(q1v, kd.w, s[1][3]);
            s[2][0] = fmaf(q2v, kd.x, s[2][0]); s[2][1] = fmaf(q2v, kd.y, s[2][1]);
            s[2][2] = fmaf(q2v, kd.z, s[2][2]); s[2][3] = fmaf(q2v, kd.w, s[2][3]);
            s[3][0] = fmaf(q3v, kd.x, s[3][0]); s[3][1] = fmaf(q3v, kd.y, s[3][1]);
            s[3][2] = fmaf(q3v, kd.z, s[3][2]); s[3][3] = fmaf(q3v, kd.w, s[3][3]);
        }

        // online softmax per row (reduce across the 16 tx lanes of a row group)
        float pout[4][4];
#pragma unroll
        for (int i = 0; i < 4; ++i) {
#pragma unroll
            for (int j = 0; j < 4; ++j) s[i][j] *= ATT_SCALE;
            float tm = fmaxf(fmaxf(s[i][0], s[i][1]), fmaxf(s[i][2], s[i][3]));
#pragma unroll
            for (int off = 1; off < 16; off <<= 1) tm = fmaxf(tm, __shfl_xor(tm, off));
            float mnew  = fmaxf(m_i[i], tm);
            float alpha = __expf(m_i[i] - mnew);
            float rsum = 0.0f;
#pragma unroll
            for (int j = 0; j < 4; ++j) {
                float p = __expf(s[i][j] - mnew);
                pout[i][j] = p;
                rsum += p;
            }
#pragma unroll
            for (int off = 1; off < 16; off <<= 1) rsum += __shfl_xor(rsum, off);
            l_i[i] = l_i[i] * alpha + rsum;
            m_i[i] = mnew;
#pragma unroll
            for (int j = 0; j < 4; ++j) o_acc[i][j] *= alpha;
        }
        __syncthreads();   // all lanes done reading Kt — safe to alias as Ps
#pragma unroll
        for (int i = 0; i < 4; ++i)
#pragma unroll
            for (int j = 0; j < 4; ++j)
                Ps[ty * 4 + i][tx * 4 + j] = pout[i][j];
        __syncthreads();   // Ps visible

        // O += P @ V  (rows ty*4..+3, d-cols tx*4..+3)
#pragma unroll 4
        for (int j = 0; j < 64; ++j) {
            float4 vv = *(const float4*)&Vs[j][tx * 4];
            float p0 = Ps[ty * 4 + 0][j];
            float p1 = Ps[ty * 4 + 1][j];
            float p2 = Ps[ty * 4 + 2][j];
            float p3 = Ps[ty * 4 + 3][j];
            o_acc[0][0] = fmaf(p0, vv.x, o_acc[0][0]); o_acc[0][1] = fmaf(p0, vv.y, o_acc[0][1]);
            o_acc[0][2] = fmaf(p0, vv.z, o_acc[0][2]); o_acc[0][3] = fmaf(p0, vv.w, o_acc[0][3]);
            o_acc[1][0] = fmaf(p1, vv.x, o_acc[1][0]); o_acc[1][1] = fmaf(p1, vv.y, o_acc[1][1]);
            o_acc[1][2] = fmaf(p1, vv.z, o_acc[1][2]); o_acc[1][3] = fmaf(p1, vv.w, o_acc[1][3]);
            o_acc[2][0] = fmaf(p2, vv.x, o_acc[2][0]); o_acc[2][1] = fmaf(p2, vv.y, o_acc[2][1]);
            o_acc[2][2] = fmaf(p2, vv.z, o_acc[2][2]); o_acc[2][3] = fmaf(p2, vv.w, o_acc[2][3]);
            o_acc[3][0] = fmaf(p3, vv.x, o_acc[3][0]); o_acc[3][1] = fmaf(p3, vv.y, o_acc[3][1]);
            o_acc[3][2] = fmaf(p3, vv.z, o_acc[3][2]); o_acc[3][3] = fmaf(p3, vv.w, o_acc[3][3]);
        }
    }

#pragma unroll
    for (int i = 0; i < 4; ++i) {
        float inv = 1.0f / l_i[i];
        size_t orow = (size_t)(b * n_q + q0 + ty * 4 + i);
        float4 o = { o_acc[i][0] * inv, o_acc[i][1] * inv,
                     o_acc[i][2] * inv, o_acc[i][3] * inv };
        *(float4*)&O[orow * DIM + h * DHEAD + tx * 4] = o;
    }
}

// ---------------------------------------------------------------------------
extern "C" void kernel_launch(void* const* d_in, const int* in_sizes, int n_in,
                              void* d_out, int out_size, void* d_ws, size_t ws_size,
                              hipStream_t stream)
{
    const float* x       = (const float*)d_in[0];
    const float* y       = (const float*)d_in[1];
    const float* sa_g    = (const float*)d_in[2];
    const float* sa_b    = (const float*)d_in[3];
    const float* sa_wqkv = (const float*)d_in[4];
    const float* sa_wo   = (const float*)d_in[5];
    const float* sa_bo   = (const float*)d_in[6];
    const float* n1_g    = (const float*)d_in[7];
    const float* n1_b    = (const float*)d_in[8];
    const float* ca_g    = (const float*)d_in[9];
    const float* ca_b    = (const float*)d_in[10];
    const float* ca_wq   = (const float*)d_in[11];
    const float* ca_wkv  = (const float*)d_in[12];
    const float* ca_wo   = (const float*)d_in[13];
    const float* ca_bo   = (const float*)d_in[14];
    const float* ff_g    = (const float*)d_in[15];
    const float* ff_b    = (const float*)d_in[16];
    const float* ff_w1   = (const float*)d_in[17];
    const float* ff_b1   = (const float*)d_in[18];
    const float* ff_w2   = (const float*)d_in[19];
    const float* ff_b2   = (const float*)d_in[20];
    float* out = (float*)d_out;
    float* ws  = (float*)d_ws;

    const int Mx = BATCH * NQ;    // 8192 rows of x
    const int My = BATCH * NKV;   // 4096 rows of y

    // workspace layout (floats); qkv and MLP-hidden share "big" (disjoint lifetime)
    float* xn   = ws;                       // 8192*512   =  4,194,304
    float* big  = ws + 4194304;             // max(8192*1536, 8192*2048) = 16,777,216
    float* attn = ws + 20971520;            // 8192*512
    float* q2   = ws + 25165824;            // 8192*512
    float* kvb  = ws + 29360128;            // 4096*1024
    // total: 33,554,432 floats = 128 MiB

    // 1) xn = LN(x, sa_g, sa_b)
    ln_kernel<<<Mx, 128, 0, stream>>>(x, sa_g, sa_b, xn);
    // 2) qkv = xn @ sa_wqkv           [8192 x 1536]
    gemm_kernel<0, 128><<<dim3(1536 / 128, Mx / 128), 256, 0, stream>>>(
        xn, sa_wqkv, nullptr, nullptr, big, Mx, 512, 1536);
    // 3) self attention (q,k,v strided views of qkv)
    attn_kernel<<<dim3(NQ / 64, BATCH * HEADS), 256, 0, stream>>>(
        big, 1536, big + 512, big + 1024, 1536, attn, NQ, NQ);
    // 4) out = x + attn @ sa_wo + sa_bo
    gemm_kernel<2, 64><<<dim3(512 / 64, Mx / 128), 256, 0, stream>>>(
        attn, sa_wo, sa_bo, x, out, Mx, 512, 512);
    // 5) xn = LN(LN(out, n1), ca)
    ln2_kernel<<<Mx, 128, 0, stream>>>(out, n1_g, n1_b, ca_g, ca_b, xn);
    // 6) q2 = xn @ ca_wq              [8192 x 512]
    gemm_kernel<0, 64><<<dim3(512 / 64, Mx / 128), 256, 0, stream>>>(
        xn, ca_wq, nullptr, nullptr, q2, Mx, 512, 512);
    // 7) kv = y @ ca_wkv              [4096 x 1024]
    gemm_kernel<0, 128><<<dim3(1024 / 128, My / 128), 256, 0, stream>>>(
        y, ca_wkv, nullptr, nullptr, kvb, My, 512, 1024);
    // 8) cross attention
    attn_kernel<<<dim3(NQ / 64, BATCH * HEADS), 256, 0, stream>>>(
        q2, 512, kvb, kvb + 512, 1024, attn, NQ, NKV);
    // 9) out = out + attn @ ca_wo + ca_bo   (in-place residual)
    gemm_kernel<2, 64><<<dim3(512 / 64, Mx / 128), 256, 0, stream>>>(
        attn, ca_wo, ca_bo, out, out, Mx, 512, 512);
    // 10) xn = LN(out, ff_g, ff_b)
    ln_kernel<<<Mx, 128, 0, stream>>>(out, ff_g, ff_b, xn);
    // 11) big = gelu(xn @ ff_w1 + ff_b1)    [8192 x 2048]
    gemm_kernel<3, 128><<<dim3(2048 / 128, Mx / 128), 256, 0, stream>>>(
        xn, ff_w1, ff_b1, nullptr, big, Mx, 512, 2048);
    // 12) out = out + big @ ff_w2 + ff_b2   [K=2048]
    gemm_kernel<2, 64><<<dim3(512 / 64, Mx / 128), 256, 0, stream>>>(
        big, ff_w2, ff_b2, out, out, Mx, 2048, 512);

    (void)in_sizes; (void)n_in; (void)out_size; (void)ws_size;
}

// Round 7
// 694.249 us; speedup vs baseline: 2.6481x; 2.6481x over previous
//
#include <hip/hip_runtime.h>
#include <hip/hip_bf16.h>
#include <math.h>

#define DIM    512
#define HEADS  8
#define DHEAD  64
#define BATCH  4
#define NQ     2048
#define NKV    1024
#define ATT_SCALE 0.125f
#define LN_EPS 1e-5f

typedef unsigned short u16;
typedef float f32x4 __attribute__((ext_vector_type(4)));
typedef short bf16x8 __attribute__((ext_vector_type(8)));

__device__ __forceinline__ u16 f2bf(float f) {
    unsigned u = __float_as_uint(f);
    u += 0x7fffu + ((u >> 16) & 1u);          // round-to-nearest-even
    return (u16)(u >> 16);
}

__device__ __forceinline__ float gelu_f(float x) {
    return 0.5f * x * (1.0f + erff(x * 0.70710678118654752440f));
}

// ---------------------------------------------------------------------------
// fp32 -> bf16 elementwise (for y)
// ---------------------------------------------------------------------------
__global__ __launch_bounds__(256)
void f2b_kernel(const float* __restrict__ in, u16* __restrict__ out, int n4)
{
    int i = blockIdx.x * 256 + threadIdx.x;
    if (i < n4) {
        float4 v = *(const float4*)&in[(size_t)i * 4];
        unsigned lo = f2bf(v.x) | ((unsigned)f2bf(v.y) << 16);
        unsigned hi = f2bf(v.z) | ((unsigned)f2bf(v.w) << 16);
        *(uint2*)&out[(size_t)i * 4] = make_uint2(lo, hi);
    }
}

// ---------------------------------------------------------------------------
// weight transpose + convert: src fp32 [K][N] -> dst bf16 [N][K]
// ---------------------------------------------------------------------------
__global__ __launch_bounds__(256)
void wtrans_kernel(const float* __restrict__ src, u16* __restrict__ dst,
                   int K, int N)
{
    __shared__ float tile[32][33];
    const int n0 = blockIdx.x * 32, k0 = blockIdx.y * 32;
    const int tx = threadIdx.x & 31, ty = threadIdx.x >> 5;   // 32 x 8
#pragma unroll
    for (int j = 0; j < 4; ++j)
        tile[ty + 8 * j][tx] = src[(size_t)(k0 + ty + 8 * j) * N + n0 + tx];
    __syncthreads();
#pragma unroll
    for (int j = 0; j < 4; ++j)
        dst[(size_t)(n0 + ty + 8 * j) * K + k0 + tx] = f2bf(tile[tx][ty + 8 * j]);
}

// ---------------------------------------------------------------------------
// LayerNorm fp32-in bf16-out. One block (128 threads) per 512-float row.
// ---------------------------------------------------------------------------
__global__ __launch_bounds__(128)
void ln_kernel(const float* __restrict__ x, const float* __restrict__ g,
               const float* __restrict__ b, u16* __restrict__ out)
{
    __shared__ float red[4];
    const int row = blockIdx.x;
    const int t = threadIdx.x;
    const int wid = t >> 6, lane = t & 63;

    float4 v = *(const float4*)&x[(size_t)row * DIM + t * 4];
    float s  = v.x + v.y + v.z + v.w;
    float sq = v.x*v.x + v.y*v.y + v.z*v.z + v.w*v.w;
#pragma unroll
    for (int off = 32; off >= 1; off >>= 1) {
        s  += __shfl_xor(s, off);
        sq += __shfl_xor(sq, off);
    }
    if (lane == 0) { red[wid] = s; red[2 + wid] = sq; }
    __syncthreads();
    s = red[0] + red[1]; sq = red[2] + red[3];

    const float mu = s * (1.0f / DIM);
    const float rs = rsqrtf(sq * (1.0f / DIM) - mu * mu + LN_EPS);
    float4 gv = *(const float4*)&g[t * 4];
    float4 bv = *(const float4*)&b[t * 4];
    float ox = (v.x - mu) * rs * gv.x + bv.x;
    float oy = (v.y - mu) * rs * gv.y + bv.y;
    float oz = (v.z - mu) * rs * gv.z + bv.z;
    float ow = (v.w - mu) * rs * gv.w + bv.w;
    unsigned lo = f2bf(ox) | ((unsigned)f2bf(oy) << 16);
    unsigned hi = f2bf(oz) | ((unsigned)f2bf(ow) << 16);
    *(uint2*)&out[(size_t)row * DIM + t * 4] = make_uint2(lo, hi);
}

// Double LayerNorm: out = LN(LN(x,g1,b1),g2,b2), bf16 out.
__global__ __launch_bounds__(128)
void ln2_kernel(const float* __restrict__ x,
                const float* __restrict__ g1, const float* __restrict__ b1,
                const float* __restrict__ g2, const float* __restrict__ b2,
                u16* __restrict__ out)
{
    __shared__ float red[4];
    const int row = blockIdx.x;
    const int t = threadIdx.x;
    const int wid = t >> 6, lane = t & 63;

    float4 v = *(const float4*)&x[(size_t)row * DIM + t * 4];
    float s  = v.x + v.y + v.z + v.w;
    float sq = v.x*v.x + v.y*v.y + v.z*v.z + v.w*v.w;
#pragma unroll
    for (int off = 32; off >= 1; off >>= 1) {
        s  += __shfl_xor(s, off);
        sq += __shfl_xor(sq, off);
    }
    if (lane == 0) { red[wid] = s; red[2 + wid] = sq; }
    __syncthreads();
    s = red[0] + red[1]; sq = red[2] + red[3];
    float mu = s * (1.0f / DIM);
    float rs = rsqrtf(sq * (1.0f / DIM) - mu * mu + LN_EPS);

    float4 g = *(const float4*)&g1[t * 4];
    float4 bb = *(const float4*)&b1[t * 4];
    float4 z;
    z.x = (v.x - mu) * rs * g.x + bb.x;
    z.y = (v.y - mu) * rs * g.y + bb.y;
    z.z = (v.z - mu) * rs * g.z + bb.z;
    z.w = (v.w - mu) * rs * g.w + bb.w;

    s  = z.x + z.y + z.z + z.w;
    sq = z.x*z.x + z.y*z.y + z.z*z.z + z.w*z.w;
#pragma unroll
    for (int off = 32; off >= 1; off >>= 1) {
        s  += __shfl_xor(s, off);
        sq += __shfl_xor(sq, off);
    }
    __syncthreads();
    if (lane == 0) { red[wid] = s; red[2 + wid] = sq; }
    __syncthreads();
    s = red[0] + red[1]; sq = red[2] + red[3];
    mu = s * (1.0f / DIM);
    rs = rsqrtf(sq * (1.0f / DIM) - mu * mu + LN_EPS);

    g  = *(const float4*)&g2[t * 4];
    bb = *(const float4*)&b2[t * 4];
    float ox = (z.x - mu) * rs * g.x + bb.x;
    float oy = (z.y - mu) * rs * g.y + bb.y;
    float oz = (z.z - mu) * rs * g.z + bb.z;
    float ow = (z.w - mu) * rs * g.w + bb.w;
    unsigned lo = f2bf(ox) | ((unsigned)f2bf(oy) << 16);
    unsigned hi = f2bf(oz) | ((unsigned)f2bf(ow) << 16);
    *(uint2*)&out[(size_t)row * DIM + t * 4] = make_uint2(lo, hi);
}

// ---------------------------------------------------------------------------
// bf16 MFMA GEMM: C[M][Nc] = A[M][K] @ BT[Nc][K]^T  (+bias)(+gelu)(+res)
// 128x128 tile, BK=32, 4 waves, each wave a 64x64 sub-tile (4x4 frags of
// 16x16x32 MFMA). fp32 accumulation. EPI: 0=bf16 out, 2=bias+res fp32 out,
// 3=bias+gelu bf16 out.
// ---------------------------------------------------------------------------
template<int EPI>
__global__ __launch_bounds__(256)
void gemm_bf16(const u16* __restrict__ A, const u16* __restrict__ BT,
               const float* __restrict__ bias, const float* __restrict__ res,
               void* __restrict__ Cv, int M, int K, int Nc)
{
    __shared__ __align__(16) u16 As[128][40];   // pad 8 bf16 -> 80B stride
    __shared__ __align__(16) u16 Bs[128][40];

    const int t    = threadIdx.x;
    const int lane = t & 63;
    const int w    = t >> 6;
    const int wr   = (w >> 1) * 64, wc = (w & 1) * 64;
    const int rlo  = lane & 15, rhi = lane >> 4;
    const int row0 = blockIdx.y * 128, col0 = blockIdx.x * 128;

    const f32x4 z4 = {0.f, 0.f, 0.f, 0.f};
    f32x4 acc[4][4];
#pragma unroll
    for (int m = 0; m < 4; ++m)
#pragma unroll
        for (int n = 0; n < 4; ++n) acc[m][n] = z4;

    uint4 pa[2], pb[2];
    const int nkt = K >> 5;

#define LOADG(kt)                                                            \
    {                                                                        \
        _Pragma("unroll")                                                    \
        for (int i = 0; i < 2; ++i) {                                        \
            int idx = i * 256 + t, r = idx >> 2, c = idx & 3;                \
            pa[i] = *(const uint4*)&A[(size_t)(row0 + r) * K + (kt)*32 + c*8];\
            pb[i] = *(const uint4*)&BT[(size_t)(col0 + r) * K + (kt)*32 + c*8];\
        }                                                                    \
    }

    LOADG(0);
    for (int kt = 0; kt < nkt; ++kt) {
        __syncthreads();
#pragma unroll
        for (int i = 0; i < 2; ++i) {
            int idx = i * 256 + t, r = idx >> 2, c = idx & 3;
            *(uint4*)&As[r][c * 8] = pa[i];
            *(uint4*)&Bs[r][c * 8] = pb[i];
        }
        __syncthreads();
        if (kt + 1 < nkt) LOADG(kt + 1);

        bf16x8 af[4], bf[4];
#pragma unroll
        for (int m = 0; m < 4; ++m)
            af[m] = *(const bf16x8*)&As[wr + m * 16 + rlo][rhi * 8];
#pragma unroll
        for (int n = 0; n < 4; ++n)
            bf[n] = *(const bf16x8*)&Bs[wc + n * 16 + rlo][rhi * 8];
#pragma unroll
        for (int m = 0; m < 4; ++m)
#pragma unroll
            for (int n = 0; n < 4; ++n)
                acc[m][n] = __builtin_amdgcn_mfma_f32_16x16x32_bf16(
                    af[m], bf[n], acc[m][n], 0, 0, 0);
    }
#undef LOADG

    float* Cf = (float*)Cv;
    u16*   Cb = (u16*)Cv;
#pragma unroll
    for (int m = 0; m < 4; ++m) {
#pragma unroll
        for (int n = 0; n < 4; ++n) {
            const int cg = col0 + wc + n * 16 + rlo;
            const float bv = (EPI >= 2) ? bias[cg] : 0.0f;
#pragma unroll
            for (int i = 0; i < 4; ++i) {
                const size_t rg = (size_t)(row0 + wr + m * 16 + rhi * 4 + i);
                float val = acc[m][n][i] + bv;
                if (EPI == 3) val = gelu_f(val);
                if (EPI == 2) {
                    val += res[rg * Nc + cg];
                    Cf[rg * Nc + cg] = val;
                } else {
                    Cb[rg * Nc + cg] = f2bf(val);
                }
            }
        }
    }
}

// ---------------------------------------------------------------------------
// bf16 MFMA flash attention. Block = 256 thr (4 waves); 64 q-rows per block
// (16 per wave); 64-token KV tiles. K row-major in LDS; V transposed with
// XOR swizzle (write & read use the same involution); P through LDS
// (wave-private rows, no extra barrier). fp32 accum, online softmax.
// ---------------------------------------------------------------------------
__global__ __launch_bounds__(256)
void attn_mfma(const u16* __restrict__ Q, int qs,
               const u16* __restrict__ K, const u16* __restrict__ V, int kvs,
               u16* __restrict__ O, int n_q, int n_k)
{
    __shared__ __align__(16) u16 Qs[64][72];
    __shared__ __align__(16) u16 Ks[64][72];
    __shared__ __align__(16) u16 VT[64][72];   // [d][kv^swz]
    __shared__ __align__(16) u16 Ps[64][72];

    const int t    = threadIdx.x;
    const int lane = t & 63;
    const int w    = t >> 6;
    const int wq   = w * 16;
    const int rlo  = lane & 15, rhi = lane >> 4;
    const int bh = blockIdx.y, b = bh >> 3, h = bh & 7;
    const int q0 = blockIdx.x * 64;

    const u16* Qb = Q + (size_t)b * n_q * qs + h * DHEAD;
    const u16* Kb = K + (size_t)b * n_k * kvs + h * DHEAD;
    const u16* Vb = V + (size_t)b * n_k * kvs + h * DHEAD;

#pragma unroll
    for (int i = 0; i < 2; ++i) {
        int idx = i * 256 + t, r = idx >> 3, c = idx & 7;
        *(uint4*)&Qs[r][c * 8] = *(const uint4*)&Qb[(size_t)(q0 + r) * qs + c * 8];
    }

    const f32x4 z4 = {0.f, 0.f, 0.f, 0.f};
    f32x4 o_acc[4] = {z4, z4, z4, z4};
    float m_i[4] = {-1e30f, -1e30f, -1e30f, -1e30f};
    float l_i[4] = {0.f, 0.f, 0.f, 0.f};

    const int ntiles = n_k >> 6;
    for (int it = 0; it < ntiles; ++it) {
        __syncthreads();   // prev tile consumed; Q visible (it==0)
#pragma unroll
        for (int i = 0; i < 2; ++i) {
            int idx = i * 256 + t, r = idx >> 3, c = idx & 7;
            *(uint4*)&Ks[r][c * 8] =
                *(const uint4*)&Kb[(size_t)(it * 64 + r) * kvs + c * 8];
            uint4 vv = *(const uint4*)&Vb[(size_t)(it * 64 + r) * kvs + c * 8];
            u16 e[8];
            *(uint4*)e = vv;
            const int kvw = r ^ ((c & 7) << 3);    // swizzled kv slot
#pragma unroll
            for (int q = 0; q < 8; ++q)
                VT[c * 8 + q][kvw] = e[q];
        }
        __syncthreads();

        // S = Q @ K^T  (16 q-rows x 64 kv)
        bf16x8 aq[2];
#pragma unroll
        for (int kb = 0; kb < 2; ++kb)
            aq[kb] = *(const bf16x8*)&Qs[wq + rlo][kb * 32 + rhi * 8];
        f32x4 s[4] = {z4, z4, z4, z4};
#pragma unroll
        for (int n = 0; n < 4; ++n)
#pragma unroll
            for (int kb = 0; kb < 2; ++kb) {
                bf16x8 bk = *(const bf16x8*)&Ks[n * 16 + rlo][kb * 32 + rhi * 8];
                s[n] = __builtin_amdgcn_mfma_f32_16x16x32_bf16(aq[kb], bk, s[n], 0, 0, 0);
            }
#pragma unroll
        for (int n = 0; n < 4; ++n) s[n] *= ATT_SCALE;

        // online softmax: row r=rhi*4+i lives in lanes sharing rhi (cols=rlo)
#pragma unroll
        for (int i = 0; i < 4; ++i) {
            float mx = fmaxf(fmaxf(s[0][i], s[1][i]), fmaxf(s[2][i], s[3][i]));
#pragma unroll
            for (int off = 1; off < 16; off <<= 1) mx = fmaxf(mx, __shfl_xor(mx, off));
            float mnew  = fmaxf(m_i[i], mx);
            float alpha = __expf(m_i[i] - mnew);
            float rsum = 0.f;
#pragma unroll
            for (int n = 0; n < 4; ++n) {
                float p = __expf(s[n][i] - mnew);
                rsum += p;
                Ps[wq + rhi * 4 + i][n * 16 + rlo] = f2bf(p);
            }
#pragma unroll
            for (int off = 1; off < 16; off <<= 1) rsum += __shfl_xor(rsum, off);
            l_i[i] = l_i[i] * alpha + rsum;
            m_i[i] = mnew;
#pragma unroll
            for (int n = 0; n < 4; ++n) o_acc[n][i] *= alpha;
        }

        // O += P @ V   (A=P from Ps, B=V^T from swizzled VT)
#pragma unroll
        for (int kb = 0; kb < 2; ++kb) {
            bf16x8 pa = *(const bf16x8*)&Ps[wq + rlo][kb * 32 + rhi * 8];
#pragma unroll
            for (int n = 0; n < 4; ++n) {
                const int d = n * 16 + rlo;
                const int kvb2 = (kb * 32 + rhi * 8) ^ (((d >> 3) & 7) << 3);
                bf16x8 bv = *(const bf16x8*)&VT[d][kvb2];
                o_acc[n] = __builtin_amdgcn_mfma_f32_16x16x32_bf16(pa, bv, o_acc[n], 0, 0, 0);
            }
        }
    }

#pragma unroll
    for (int i = 0; i < 4; ++i) {
        const float inv = 1.0f / l_i[i];
        const size_t orow = ((size_t)b * n_q + q0 + wq + rhi * 4 + i) * DIM + h * DHEAD;
#pragma unroll
        for (int n = 0; n < 4; ++n)
            O[orow + n * 16 + rlo] = f2bf(o_acc[n][i] * inv);
    }
}

// ---------------------------------------------------------------------------
extern "C" void kernel_launch(void* const* d_in, const int* in_sizes, int n_in,
                              void* d_out, int out_size, void* d_ws, size_t ws_size,
                              hipStream_t stream)
{
    const float* x       = (const float*)d_in[0];
    const float* y       = (const float*)d_in[1];
    const float* sa_g    = (const float*)d_in[2];
    const float* sa_b    = (const float*)d_in[3];
    const float* sa_wqkv = (const float*)d_in[4];
    const float* sa_wo   = (const float*)d_in[5];
    const float* sa_bo   = (const float*)d_in[6];
    const float* n1_g    = (const float*)d_in[7];
    const float* n1_b    = (const float*)d_in[8];
    const float* ca_g    = (const float*)d_in[9];
    const float* ca_b    = (const float*)d_in[10];
    const float* ca_wq   = (const float*)d_in[11];
    const float* ca_wkv  = (const float*)d_in[12];
    const float* ca_wo   = (const float*)d_in[13];
    const float* ca_bo   = (const float*)d_in[14];
    const float* ff_g    = (const float*)d_in[15];
    const float* ff_b    = (const float*)d_in[16];
    const float* ff_w1   = (const float*)d_in[17];
    const float* ff_b1   = (const float*)d_in[18];
    const float* ff_w2   = (const float*)d_in[19];
    const float* ff_b2   = (const float*)d_in[20];
    float* out = (float*)d_out;

    const int Mx = BATCH * NQ;    // 8192
    const int My = BATCH * NKV;   // 4096

    // workspace (bf16/u16 units), total 39,845,888 u16 = 76 MiB
    u16* xb    = (u16*)d_ws;            // 4,194,304  (LN output)
    u16* bigb  = xb    + 4194304;       // 16,777,216 (qkv 12.6M / ff hidden 16.8M)
    u16* attb  = bigb  + 16777216;      // 4,194,304  (attention output)
    u16* q2b   = attb  + 4194304;       // 4,194,304
    u16* kvb   = q2b   + 4194304;       // 4,194,304
    u16* ybb   = kvb   + 4194304;       // 2,097,152
    u16* wqkvT = ybb   + 2097152;       // 786,432
    u16* woT   = wqkvT + 786432;        // 262,144
    u16* caqT  = woT   + 262144;        // 262,144
    u16* cakvT = caqT  + 262144;        // 524,288
    u16* caoT  = cakvT + 524288;        // 262,144
    u16* w1T   = caoT  + 262144;        // 1,048,576
    u16* w2T   = w1T   + 1048576;       // 1,048,576

    // --- prep: convert y, transpose+convert weights ---
    f2b_kernel<<<(My * DIM / 4 + 255) / 256, 256, 0, stream>>>(y, ybb, My * DIM / 4);
    wtrans_kernel<<<dim3(1536 / 32, 512 / 32),  256, 0, stream>>>(sa_wqkv, wqkvT, 512, 1536);
    wtrans_kernel<<<dim3(512 / 32,  512 / 32),  256, 0, stream>>>(sa_wo,   woT,   512, 512);
    wtrans_kernel<<<dim3(512 / 32,  512 / 32),  256, 0, stream>>>(ca_wq,   caqT,  512, 512);
    wtrans_kernel<<<dim3(1024 / 32, 512 / 32),  256, 0, stream>>>(ca_wkv,  cakvT, 512, 1024);
    wtrans_kernel<<<dim3(512 / 32,  512 / 32),  256, 0, stream>>>(ca_wo,   caoT,  512, 512);
    wtrans_kernel<<<dim3(2048 / 32, 512 / 32),  256, 0, stream>>>(ff_w1,   w1T,   512, 2048);
    wtrans_kernel<<<dim3(512 / 32,  2048 / 32), 256, 0, stream>>>(ff_w2,   w2T,   2048, 512);

    // --- self-attention ---
    ln_kernel<<<Mx, 128, 0, stream>>>(x, sa_g, sa_b, xb);
    gemm_bf16<0><<<dim3(1536 / 128, Mx / 128), 256, 0, stream>>>(
        xb, wqkvT, nullptr, nullptr, bigb, Mx, 512, 1536);
    attn_mfma<<<dim3(NQ / 64, BATCH * HEADS), 256, 0, stream>>>(
        bigb, 1536, bigb + 512, bigb + 1024, 1536, attb, NQ, NQ);
    gemm_bf16<2><<<dim3(512 / 128, Mx / 128), 256, 0, stream>>>(
        attb, woT, sa_bo, x, out, Mx, 512, 512);

    // --- cross-attention ---
    ln2_kernel<<<Mx, 128, 0, stream>>>(out, n1_g, n1_b, ca_g, ca_b, xb);
    gemm_bf16<0><<<dim3(512 / 128, Mx / 128), 256, 0, stream>>>(
        xb, caqT, nullptr, nullptr, q2b, Mx, 512, 512);
    gemm_bf16<0><<<dim3(1024 / 128, My / 128), 256, 0, stream>>>(
        ybb, cakvT, nullptr, nullptr, kvb, My, 512, 1024);
    attn_mfma<<<dim3(NQ / 64, BATCH * HEADS), 256, 0, stream>>>(
        q2b, 512, kvb, kvb + 512, 1024, attb, NQ, NKV);
    gemm_bf16<2><<<dim3(512 / 128, Mx / 128), 256, 0, stream>>>(
        attb, caoT, ca_bo, out, out, Mx, 512, 512);

    // --- MLP ---
    ln_kernel<<<Mx, 128, 0, stream>>>(out, ff_g, ff_b, xb);
    gemm_bf16<3><<<dim3(2048 / 128, Mx / 128), 256, 0, stream>>>(
        xb, w1T, ff_b1, nullptr, bigb, Mx, 512, 2048);
    gemm_bf16<2><<<dim3(512 / 128, Mx / 128), 256, 0, stream>>>(
        bigb, w2T, ff_b2, out, out, Mx, 2048, 512);

    (void)in_sizes; (void)n_in; (void)out_size; (void)ws_size;
}

// Round 8
// 587.856 us; speedup vs baseline: 3.1273x; 1.1810x over previous
//
#include <hip/hip_runtime.h>
#include <hip/hip_bf16.h>
#include <math.h>

#define DIM    512
#define HEADS  8
#define DHEAD  64
#define BATCH  4
#define NQ     2048
#define NKV    1024
#define ATT_SCALE 0.125f
#define LN_EPS 1e-5f

typedef unsigned short u16;
typedef float f32x4  __attribute__((ext_vector_type(4)));
typedef float f32x16 __attribute__((ext_vector_type(16)));
typedef short bf16x8 __attribute__((ext_vector_type(8)));

__device__ __forceinline__ u16 f2bf(float f) {
    unsigned u = __float_as_uint(f);
    u += 0x7fffu + ((u >> 16) & 1u);          // round-to-nearest-even
    return (u16)(u >> 16);
}

__device__ __forceinline__ unsigned cvtpk_bf16(float lo, float hi) {
    unsigned r;
    asm("v_cvt_pk_bf16_f32 %0, %1, %2" : "=v"(r) : "v"(lo), "v"(hi));
    return r;
}

__device__ __forceinline__ float gelu_f(float x) {
    return 0.5f * x * (1.0f + erff(x * 0.70710678118654752440f));
}

// ---------------------------------------------------------------------------
// fp32 -> bf16 elementwise (for y)
// ---------------------------------------------------------------------------
__global__ __launch_bounds__(256)
void f2b_kernel(const float* __restrict__ in, u16* __restrict__ out, int n4)
{
    int i = blockIdx.x * 256 + threadIdx.x;
    if (i < n4) {
        float4 v = *(const float4*)&in[(size_t)i * 4];
        unsigned lo = f2bf(v.x) | ((unsigned)f2bf(v.y) << 16);
        unsigned hi = f2bf(v.z) | ((unsigned)f2bf(v.w) << 16);
        *(uint2*)&out[(size_t)i * 4] = make_uint2(lo, hi);
    }
}

// ---------------------------------------------------------------------------
// weight transpose + convert: src fp32 [K][N] -> dst bf16 [N][K]
// ---------------------------------------------------------------------------
__global__ __launch_bounds__(256)
void wtrans_kernel(const float* __restrict__ src, u16* __restrict__ dst,
                   int K, int N)
{
    __shared__ float tile[32][33];
    const int n0 = blockIdx.x * 32, k0 = blockIdx.y * 32;
    const int tx = threadIdx.x & 31, ty = threadIdx.x >> 5;   // 32 x 8
#pragma unroll
    for (int j = 0; j < 4; ++j)
        tile[ty + 8 * j][tx] = src[(size_t)(k0 + ty + 8 * j) * N + n0 + tx];
    __syncthreads();
#pragma unroll
    for (int j = 0; j < 4; ++j)
        dst[(size_t)(n0 + ty + 8 * j) * K + k0 + tx] = f2bf(tile[tx][ty + 8 * j]);
}

// ---------------------------------------------------------------------------
// LayerNorm fp32-in bf16-out. One block (128 threads) per 512-float row.
// ---------------------------------------------------------------------------
__global__ __launch_bounds__(128)
void ln_kernel(const float* __restrict__ x, const float* __restrict__ g,
               const float* __restrict__ b, u16* __restrict__ out)
{
    __shared__ float red[4];
    const int row = blockIdx.x;
    const int t = threadIdx.x;
    const int wid = t >> 6, lane = t & 63;

    float4 v = *(const float4*)&x[(size_t)row * DIM + t * 4];
    float s  = v.x + v.y + v.z + v.w;
    float sq = v.x*v.x + v.y*v.y + v.z*v.z + v.w*v.w;
#pragma unroll
    for (int off = 32; off >= 1; off >>= 1) {
        s  += __shfl_xor(s, off);
        sq += __shfl_xor(sq, off);
    }
    if (lane == 0) { red[wid] = s; red[2 + wid] = sq; }
    __syncthreads();
    s = red[0] + red[1]; sq = red[2] + red[3];

    const float mu = s * (1.0f / DIM);
    const float rs = rsqrtf(sq * (1.0f / DIM) - mu * mu + LN_EPS);
    float4 gv = *(const float4*)&g[t * 4];
    float4 bv = *(const float4*)&b[t * 4];
    float ox = (v.x - mu) * rs * gv.x + bv.x;
    float oy = (v.y - mu) * rs * gv.y + bv.y;
    float oz = (v.z - mu) * rs * gv.z + bv.z;
    float ow = (v.w - mu) * rs * gv.w + bv.w;
    unsigned lo = f2bf(ox) | ((unsigned)f2bf(oy) << 16);
    unsigned hi = f2bf(oz) | ((unsigned)f2bf(ow) << 16);
    *(uint2*)&out[(size_t)row * DIM + t * 4] = make_uint2(lo, hi);
}

// Double LayerNorm: out = LN(LN(x,g1,b1),g2,b2), bf16 out.
__global__ __launch_bounds__(128)
void ln2_kernel(const float* __restrict__ x,
                const float* __restrict__ g1, const float* __restrict__ b1,
                const float* __restrict__ g2, const float* __restrict__ b2,
                u16* __restrict__ out)
{
    __shared__ float red[4];
    const int row = blockIdx.x;
    const int t = threadIdx.x;
    const int wid = t >> 6, lane = t & 63;

    float4 v = *(const float4*)&x[(size_t)row * DIM + t * 4];
    float s  = v.x + v.y + v.z + v.w;
    float sq = v.x*v.x + v.y*v.y + v.z*v.z + v.w*v.w;
#pragma unroll
    for (int off = 32; off >= 1; off >>= 1) {
        s  += __shfl_xor(s, off);
        sq += __shfl_xor(sq, off);
    }
    if (lane == 0) { red[wid] = s; red[2 + wid] = sq; }
    __syncthreads();
    s = red[0] + red[1]; sq = red[2] + red[3];
    float mu = s * (1.0f / DIM);
    float rs = rsqrtf(sq * (1.0f / DIM) - mu * mu + LN_EPS);

    float4 g = *(const float4*)&g1[t * 4];
    float4 bb = *(const float4*)&b1[t * 4];
    float4 z;
    z.x = (v.x - mu) * rs * g.x + bb.x;
    z.y = (v.y - mu) * rs * g.y + bb.y;
    z.z = (v.z - mu) * rs * g.z + bb.z;
    z.w = (v.w - mu) * rs * g.w + bb.w;

    s  = z.x + z.y + z.z + z.w;
    sq = z.x*z.x + z.y*z.y + z.z*z.z + z.w*z.w;
#pragma unroll
    for (int off = 32; off >= 1; off >>= 1) {
        s  += __shfl_xor(s, off);
        sq += __shfl_xor(sq, off);
    }
    __syncthreads();
    if (lane == 0) { red[wid] = s; red[2 + wid] = sq; }
    __syncthreads();
    s = red[0] + red[1]; sq = red[2] + red[3];
    mu = s * (1.0f / DIM);
    rs = rsqrtf(sq * (1.0f / DIM) - mu * mu + LN_EPS);

    g  = *(const float4*)&g2[t * 4];
    bb = *(const float4*)&b2[t * 4];
    float ox = (z.x - mu) * rs * g.x + bb.x;
    float oy = (z.y - mu) * rs * g.y + bb.y;
    float oz = (z.z - mu) * rs * g.z + bb.z;
    float ow = (z.w - mu) * rs * g.w + bb.w;
    unsigned lo = f2bf(ox) | ((unsigned)f2bf(oy) << 16);
    unsigned hi = f2bf(oz) | ((unsigned)f2bf(ow) << 16);
    *(uint2*)&out[(size_t)row * DIM + t * 4] = make_uint2(lo, hi);
}

// ---------------------------------------------------------------------------
// bf16 MFMA GEMM: C[M][Nc] = A[M][K] @ BT[Nc][K]^T  (+bias)(+gelu)(+res)
// 128x128 tile, BK=32, 4 waves, each wave a 64x64 sub-tile (4x4 frags of
// 16x16x32 MFMA). fp32 accumulation. EPI: 0=bf16 out, 2=bias+res fp32 out,
// 3=bias+gelu bf16 out.   (unchanged from round 7 — measured good)
// ---------------------------------------------------------------------------
template<int EPI>
__global__ __launch_bounds__(256)
void gemm_bf16(const u16* __restrict__ A, const u16* __restrict__ BT,
               const float* __restrict__ bias, const float* __restrict__ res,
               void* __restrict__ Cv, int M, int K, int Nc)
{
    __shared__ __align__(16) u16 As[128][40];   // pad 8 bf16 -> 80B stride
    __shared__ __align__(16) u16 Bs[128][40];

    const int t    = threadIdx.x;
    const int lane = t & 63;
    const int w    = t >> 6;
    const int wr   = (w >> 1) * 64, wc = (w & 1) * 64;
    const int rlo  = lane & 15, rhi = lane >> 4;
    const int row0 = blockIdx.y * 128, col0 = blockIdx.x * 128;

    const f32x4 z4 = {0.f, 0.f, 0.f, 0.f};
    f32x4 acc[4][4];
#pragma unroll
    for (int m = 0; m < 4; ++m)
#pragma unroll
        for (int n = 0; n < 4; ++n) acc[m][n] = z4;

    uint4 pa[2], pb[2];
    const int nkt = K >> 5;

#define LOADG(kt)                                                            \
    {                                                                        \
        _Pragma("unroll")                                                    \
        for (int i = 0; i < 2; ++i) {                                        \
            int idx = i * 256 + t, r = idx >> 2, c = idx & 3;                \
            pa[i] = *(const uint4*)&A[(size_t)(row0 + r) * K + (kt)*32 + c*8];\
            pb[i] = *(const uint4*)&BT[(size_t)(col0 + r) * K + (kt)*32 + c*8];\
        }                                                                    \
    }

    LOADG(0);
    for (int kt = 0; kt < nkt; ++kt) {
        __syncthreads();
#pragma unroll
        for (int i = 0; i < 2; ++i) {
            int idx = i * 256 + t, r = idx >> 2, c = idx & 3;
            *(uint4*)&As[r][c * 8] = pa[i];
            *(uint4*)&Bs[r][c * 8] = pb[i];
        }
        __syncthreads();
        if (kt + 1 < nkt) LOADG(kt + 1);

        bf16x8 af[4], bf[4];
#pragma unroll
        for (int m = 0; m < 4; ++m)
            af[m] = *(const bf16x8*)&As[wr + m * 16 + rlo][rhi * 8];
#pragma unroll
        for (int n = 0; n < 4; ++n)
            bf[n] = *(const bf16x8*)&Bs[wc + n * 16 + rlo][rhi * 8];
#pragma unroll
        for (int m = 0; m < 4; ++m)
#pragma unroll
            for (int n = 0; n < 4; ++n)
                acc[m][n] = __builtin_amdgcn_mfma_f32_16x16x32_bf16(
                    af[m], bf[n], acc[m][n], 0, 0, 0);
    }
#undef LOADG

    float* Cf = (float*)Cv;
    u16*   Cb = (u16*)Cv;
#pragma unroll
    for (int m = 0; m < 4; ++m) {
#pragma unroll
        for (int n = 0; n < 4; ++n) {
            const int cg = col0 + wc + n * 16 + rlo;
            const float bv = (EPI >= 2) ? bias[cg] : 0.0f;
#pragma unroll
            for (int i = 0; i < 4; ++i) {
                const size_t rg = (size_t)(row0 + wr + m * 16 + rhi * 4 + i);
                float val = acc[m][n][i] + bv;
                if (EPI == 3) val = gelu_f(val);
                if (EPI == 2) {
                    val += res[rg * Nc + cg];
                    Cf[rg * Nc + cg] = val;
                } else {
                    Cb[rg * Nc + cg] = f2bf(val);
                }
            }
        }
    }
}

// ---------------------------------------------------------------------------
// bf16 MFMA flash attention v2 — 32x32 swapped-operand form.
// 4 waves x 32 q-rows; KVBLK=64. S^T = mfma(K, Q): lane owns q=lane&31's
// P-row (split with lane^32). Softmax fully in-register, exp2-domain with
// scale*log2e folded into Q frags; defer-max (THR=5). P -> PV B-fragment via
// cvt_pk_bf16 + v_permlane32_swap. O = mfma(V^T, P): col=q again, so the
// alpha rescale is in-lane. Only K and swizzled V^T go through LDS.
// ---------------------------------------------------------------------------
__global__ __launch_bounds__(256)
void attn_mfma2(const u16* __restrict__ Q, int qs,
                const u16* __restrict__ K, const u16* __restrict__ V, int kvs,
                u16* __restrict__ O, int n_q, int n_k)
{
    __shared__ __align__(16) u16 Ks[64][72];
    __shared__ __align__(16) u16 VT[64][72];   // [d][kv ^ ((d>>3)<<3)]

    const int t    = threadIdx.x;
    const int lane = t & 63;
    const int w    = t >> 6;          // wave id: q rows [w*32, w*32+32)
    const int ql   = lane & 31;
    const int hi   = lane >> 5;
    const int bh = blockIdx.y, b = bh >> 3, h = bh & 7;
    const int q0 = blockIdx.x * 128;

    const u16* Qb = Q + (size_t)b * n_q * qs + h * DHEAD;
    const u16* Kb = K + (size_t)b * n_k * kvs + h * DHEAD;
    const u16* Vb = V + (size_t)b * n_k * kvs + h * DHEAD;

    // Q fragments (B operand, row=lane&31=q, k=hi*8+j), pre-scaled.
    const float QSC = ATT_SCALE * 1.44269504088896f;   // scale * log2(e)
    bf16x8 qf[4];
    {
        const u16* Qrow = Qb + (size_t)(q0 + w * 32 + ql) * qs;
#pragma unroll
        for (int kb = 0; kb < 4; ++kb) {
            uint4 raw = *(const uint4*)&Qrow[kb * 16 + hi * 8];
            u16 e[8]; *(uint4*)e = raw;
            union { unsigned u[4]; bf16x8 v; } uq;
#pragma unroll
            for (int j = 0; j < 4; ++j) {
                float lo = __uint_as_float((unsigned)e[2*j]     << 16) * QSC;
                float hf = __uint_as_float((unsigned)e[2*j + 1] << 16) * QSC;
                uq.u[j] = cvtpk_bf16(lo, hf);
            }
            qf[kb] = uq.v;
        }
    }

    const f32x16 z16 = {0.f,0.f,0.f,0.f,0.f,0.f,0.f,0.f,
                        0.f,0.f,0.f,0.f,0.f,0.f,0.f,0.f};
    f32x16 oa0 = z16, oa1 = z16;      // O[q=ql][d]: d = (r&3)+8*(r>>2)+4*hi (+32)
    float m = -1e30f, l = 0.f;

    const int ntiles = n_k >> 6;
    for (int it = 0; it < ntiles; ++it) {
        __syncthreads();   // prev tile consumed
#pragma unroll
        for (int i = 0; i < 2; ++i) {
            int idx = i * 256 + t, r = idx >> 3, c = idx & 7;
            *(uint4*)&Ks[r][c * 8] =
                *(const uint4*)&Kb[(size_t)(it * 64 + r) * kvs + c * 8];
            uint4 vv = *(const uint4*)&Vb[(size_t)(it * 64 + r) * kvs + c * 8];
            u16 e[8]; *(uint4*)e = vv;
            const int kvw = r ^ ((c & 7) << 3);
#pragma unroll
            for (int q = 0; q < 8; ++q)
                VT[c * 8 + q][kvw] = e[q];
        }
        __syncthreads();

        // S' = (Q*scale*log2e) @ K^T via mfma(K, Q); two 32-kv subtiles
        f32x16 s0 = z16, s1 = z16;
#pragma unroll
        for (int kb = 0; kb < 4; ++kb) {
            bf16x8 a0 = *(const bf16x8*)&Ks[ql]     [kb * 16 + hi * 8];
            bf16x8 a1 = *(const bf16x8*)&Ks[32 + ql][kb * 16 + hi * 8];
            s0 = __builtin_amdgcn_mfma_f32_32x32x16_bf16(a0, qf[kb], s0, 0, 0, 0);
            s1 = __builtin_amdgcn_mfma_f32_32x32x16_bf16(a1, qf[kb], s1, 0, 0, 0);
        }

        // row-max over this tile (in-register tree + one half-swap)
        float a[16];
#pragma unroll
        for (int i = 0; i < 16; ++i) a[i] = fmaxf(s0[i], s1[i]);
#pragma unroll
        for (int i = 0; i < 8; ++i) a[i] = fmaxf(a[i], a[i + 8]);
#pragma unroll
        for (int i = 0; i < 4; ++i) a[i] = fmaxf(a[i], a[i + 4]);
        a[0] = fmaxf(a[0], a[2]); a[1] = fmaxf(a[1], a[3]);
        a[0] = fmaxf(a[0], a[1]);
        float pmax = fmaxf(a[0], __shfl_xor(a[0], 32));

        // defer-max: skip rescale while tile max is within 5 (log2) of m
        if (!__all(pmax - m <= 5.0f)) {
            float mn = fmaxf(m, pmax);
            float al = __builtin_amdgcn_exp2f(m - mn);
            l *= al; oa0 *= al; oa1 *= al;
            m = mn;
        }

        f32x16 pe0, pe1;
        float sc[16];
#pragma unroll
        for (int i = 0; i < 16; ++i) {
            pe0[i] = __builtin_amdgcn_exp2f(s0[i] - m);
            pe1[i] = __builtin_amdgcn_exp2f(s1[i] - m);
            sc[i]  = pe0[i] + pe1[i];
        }
#pragma unroll
        for (int i = 0; i < 8; ++i) sc[i] += sc[i + 8];
#pragma unroll
        for (int i = 0; i < 4; ++i) sc[i] += sc[i + 4];
        float rsum = (sc[0] + sc[1]) + (sc[2] + sc[3]);
        rsum += __shfl_xor(rsum, 32);
        l += rsum;

        // PV: O += mfma(V^T, P) per 16-kv window. P frag built in-register:
        // X'=[X.lo|Y.lo] (words 0,1), Y'=[X.hi|Y.hi] (words 4,5) per swap.
#define PV_STEP(PE, KB2)                                                     \
        {                                                                    \
            const int w2 = ((KB2) & 1) * 8;                                  \
            unsigned Xw = cvtpk_bf16(PE[w2 + 0], PE[w2 + 1]);                \
            unsigned Zw = cvtpk_bf16(PE[w2 + 2], PE[w2 + 3]);                \
            unsigned Yw = cvtpk_bf16(PE[w2 + 4], PE[w2 + 5]);                \
            unsigned Ww = cvtpk_bf16(PE[w2 + 6], PE[w2 + 7]);                \
            asm volatile("v_permlane32_swap_b32 %0, %1"                      \
                         : "+v"(Yw), "+v"(Xw));                              \
            asm volatile("v_permlane32_swap_b32 %0, %1"                      \
                         : "+v"(Ww), "+v"(Zw));                              \
            union { unsigned u[4]; bf16x8 v; } pa_;                          \
            pa_.u[0] = Xw; pa_.u[1] = Zw; pa_.u[2] = Yw; pa_.u[3] = Ww;      \
            {                                                                \
                const int d0 = ql;                                           \
                const int c0 = ((KB2) * 16 + hi * 8) ^ (((d0 >> 3) & 7) << 3);\
                bf16x8 vb = *(const bf16x8*)&VT[d0][c0];                     \
                oa0 = __builtin_amdgcn_mfma_f32_32x32x16_bf16(vb, pa_.v, oa0, 0, 0, 0); \
            }                                                                \
            {                                                                \
                const int d1 = 32 + ql;                                      \
                const int c1 = ((KB2) * 16 + hi * 8) ^ (((d1 >> 3) & 7) << 3);\
                bf16x8 vb = *(const bf16x8*)&VT[d1][c1];                     \
                oa1 = __builtin_amdgcn_mfma_f32_32x32x16_bf16(vb, pa_.v, oa1, 0, 0, 0); \
            }                                                                \
        }
        PV_STEP(pe0, 0)
        PV_STEP(pe0, 1)
        PV_STEP(pe1, 2)
        PV_STEP(pe1, 3)
#undef PV_STEP
    }

    // epilogue: O[q][d] — lane owns row q=ql; d = 8g+4hi+i (+32 for oa1)
    const float inv = 1.0f / l;
    const size_t orow = (size_t)b * n_q + q0 + w * 32 + ql;
    u16* Op = O + orow * DIM + h * DHEAD;
#pragma unroll
    for (int g = 0; g < 4; ++g) {
        const int dbase = 8 * g + 4 * hi;
        unsigned w0 = cvtpk_bf16(oa0[4*g + 0] * inv, oa0[4*g + 1] * inv);
        unsigned w1 = cvtpk_bf16(oa0[4*g + 2] * inv, oa0[4*g + 3] * inv);
        *(uint2*)&Op[dbase] = make_uint2(w0, w1);
        unsigned w2 = cvtpk_bf16(oa1[4*g + 0] * inv, oa1[4*g + 1] * inv);
        unsigned w3 = cvtpk_bf16(oa1[4*g + 2] * inv, oa1[4*g + 3] * inv);
        *(uint2*)&Op[32 + dbase] = make_uint2(w2, w3);
    }
}

// ---------------------------------------------------------------------------
extern "C" void kernel_launch(void* const* d_in, const int* in_sizes, int n_in,
                              void* d_out, int out_size, void* d_ws, size_t ws_size,
                              hipStream_t stream)
{
    const float* x       = (const float*)d_in[0];
    const float* y       = (const float*)d_in[1];
    const float* sa_g    = (const float*)d_in[2];
    const float* sa_b    = (const float*)d_in[3];
    const float* sa_wqkv = (const float*)d_in[4];
    const float* sa_wo   = (const float*)d_in[5];
    const float* sa_bo   = (const float*)d_in[6];
    const float* n1_g    = (const float*)d_in[7];
    const float* n1_b    = (const float*)d_in[8];
    const float* ca_g    = (const float*)d_in[9];
    const float* ca_b    = (const float*)d_in[10];
    const float* ca_wq   = (const float*)d_in[11];
    const float* ca_wkv  = (const float*)d_in[12];
    const float* ca_wo   = (const float*)d_in[13];
    const float* ca_bo   = (const float*)d_in[14];
    const float* ff_g    = (const float*)d_in[15];
    const float* ff_b    = (const float*)d_in[16];
    const float* ff_w1   = (const float*)d_in[17];
    const float* ff_b1   = (const float*)d_in[18];
    const float* ff_w2   = (const float*)d_in[19];
    const float* ff_b2   = (const float*)d_in[20];
    float* out = (float*)d_out;

    const int Mx = BATCH * NQ;    // 8192
    const int My = BATCH * NKV;   // 4096

    // workspace (bf16/u16 units), total 39,845,888 u16 = 76 MiB
    u16* xb    = (u16*)d_ws;            // 4,194,304  (LN output)
    u16* bigb  = xb    + 4194304;       // 16,777,216 (qkv 12.6M / ff hidden 16.8M)
    u16* attb  = bigb  + 16777216;      // 4,194,304  (attention output)
    u16* q2b   = attb  + 4194304;       // 4,194,304
    u16* kvb   = q2b   + 4194304;       // 4,194,304
    u16* ybb   = kvb   + 4194304;       // 2,097,152
    u16* wqkvT = ybb   + 2097152;       // 786,432
    u16* woT   = wqkvT + 786432;        // 262,144
    u16* caqT  = woT   + 262144;        // 262,144
    u16* cakvT = caqT  + 262144;        // 524,288
    u16* caoT  = cakvT + 524288;        // 262,144
    u16* w1T   = caoT  + 262144;        // 1,048,576
    u16* w2T   = w1T   + 1048576;       // 1,048,576

    // --- prep: convert y, transpose+convert weights ---
    f2b_kernel<<<(My * DIM / 4 + 255) / 256, 256, 0, stream>>>(y, ybb, My * DIM / 4);
    wtrans_kernel<<<dim3(1536 / 32, 512 / 32),  256, 0, stream>>>(sa_wqkv, wqkvT, 512, 1536);
    wtrans_kernel<<<dim3(512 / 32,  512 / 32),  256, 0, stream>>>(sa_wo,   woT,   512, 512);
    wtrans_kernel<<<dim3(512 / 32,  512 / 32),  256, 0, stream>>>(ca_wq,   caqT,  512, 512);
    wtrans_kernel<<<dim3(1024 / 32, 512 / 32),  256, 0, stream>>>(ca_wkv,  cakvT, 512, 1024);
    wtrans_kernel<<<dim3(512 / 32,  512 / 32),  256, 0, stream>>>(ca_wo,   caoT,  512, 512);
    wtrans_kernel<<<dim3(2048 / 32, 512 / 32),  256, 0, stream>>>(ff_w1,   w1T,   512, 2048);
    wtrans_kernel<<<dim3(512 / 32,  2048 / 32), 256, 0, stream>>>(ff_w2,   w2T,   2048, 512);

    // --- self-attention ---
    ln_kernel<<<Mx, 128, 0, stream>>>(x, sa_g, sa_b, xb);
    gemm_bf16<0><<<dim3(1536 / 128, Mx / 128), 256, 0, stream>>>(
        xb, wqkvT, nullptr, nullptr, bigb, Mx, 512, 1536);
    attn_mfma2<<<dim3(NQ / 128, BATCH * HEADS), 256, 0, stream>>>(
        bigb, 1536, bigb + 512, bigb + 1024, 1536, attb, NQ, NQ);
    gemm_bf16<2><<<dim3(512 / 128, Mx / 128), 256, 0, stream>>>(
        attb, woT, sa_bo, x, out, Mx, 512, 512);

    // --- cross-attention ---
    ln2_kernel<<<Mx, 128, 0, stream>>>(out, n1_g, n1_b, ca_g, ca_b, xb);
    gemm_bf16<0><<<dim3(512 / 128, Mx / 128), 256, 0, stream>>>(
        xb, caqT, nullptr, nullptr, q2b, Mx, 512, 512);
    gemm_bf16<0><<<dim3(1024 / 128, My / 128), 256, 0, stream>>>(
        ybb, cakvT, nullptr, nullptr, kvb, My, 512, 1024);
    attn_mfma2<<<dim3(NQ / 128, BATCH * HEADS), 256, 0, stream>>>(
        q2b, 512, kvb, kvb + 512, 1024, attb, NQ, NKV);
    gemm_bf16<2><<<dim3(512 / 128, Mx / 128), 256, 0, stream>>>(
        attb, caoT, ca_bo, out, out, Mx, 512, 512);

    // --- MLP ---
    ln_kernel<<<Mx, 128, 0, stream>>>(out, ff_g, ff_b, xb);
    gemm_bf16<3><<<dim3(2048 / 128, Mx / 128), 256, 0, stream>>>(
        xb, w1T, ff_b1, nullptr, bigb, Mx, 512, 2048);
    gemm_bf16<2><<<dim3(512 / 128, Mx / 128), 256, 0, stream>>>(
        bigb, w2T, ff_b2, out, out, Mx, 2048, 512);

    (void)in_sizes; (void)n_in; (void)out_size; (void)ws_size;
}

// Round 13
// 582.496 us; speedup vs baseline: 3.1561x; 1.0092x over previous
//
#include <hip/hip_runtime.h>
#include <hip/hip_bf16.h>
#include <math.h>

#define DIM    512
#define HEADS  8
#define DHEAD  64
#define BATCH  4
#define NQ     2048
#define NKV    1024
#define ATT_SCALE 0.125f
#define LN_EPS 1e-5f

typedef unsigned short u16;
typedef float f32x4  __attribute__((ext_vector_type(4)));
typedef float f32x16 __attribute__((ext_vector_type(16)));
typedef short bf16x8 __attribute__((ext_vector_type(8)));

__device__ __forceinline__ u16 f2bf(float f) {
    unsigned u = __float_as_uint(f);
    u += 0x7fffu + ((u >> 16) & 1u);          // round-to-nearest-even
    return (u16)(u >> 16);
}

__device__ __forceinline__ unsigned cvtpk_bf16(float lo, float hi) {
    unsigned r;
    asm("v_cvt_pk_bf16_f32 %0, %1, %2" : "=v"(r) : "v"(lo), "v"(hi));
    return r;
}

__device__ __forceinline__ float gelu_f(float x) {
    return 0.5f * x * (1.0f + erff(x * 0.70710678118654752440f));
}

// ---------------------------------------------------------------------------
// fp32 -> bf16 elementwise (for y)
// ---------------------------------------------------------------------------
__global__ __launch_bounds__(256)
void f2b_kernel(const float* __restrict__ in, u16* __restrict__ out, int n4)
{
    int i = blockIdx.x * 256 + threadIdx.x;
    if (i < n4) {
        float4 v = *(const float4*)&in[(size_t)i * 4];
        unsigned lo = f2bf(v.x) | ((unsigned)f2bf(v.y) << 16);
        unsigned hi = f2bf(v.z) | ((unsigned)f2bf(v.w) << 16);
        *(uint2*)&out[(size_t)i * 4] = make_uint2(lo, hi);
    }
}

// ---------------------------------------------------------------------------
// weight transpose + convert: src fp32 [K][N] -> dst bf16 [N][K]
// ---------------------------------------------------------------------------
__global__ __launch_bounds__(256)
void wtrans_kernel(const float* __restrict__ src, u16* __restrict__ dst,
                   int K, int N)
{
    __shared__ float tile[32][33];
    const int n0 = blockIdx.x * 32, k0 = blockIdx.y * 32;
    const int tx = threadIdx.x & 31, ty = threadIdx.x >> 5;   // 32 x 8
#pragma unroll
    for (int j = 0; j < 4; ++j)
        tile[ty + 8 * j][tx] = src[(size_t)(k0 + ty + 8 * j) * N + n0 + tx];
    __syncthreads();
#pragma unroll
    for (int j = 0; j < 4; ++j)
        dst[(size_t)(n0 + ty + 8 * j) * K + k0 + tx] = f2bf(tile[tx][ty + 8 * j]);
}

// ---------------------------------------------------------------------------
// LayerNorm fp32-in bf16-out. One block (128 threads) per 512-float row.
// ---------------------------------------------------------------------------
__global__ __launch_bounds__(128)
void ln_kernel(const float* __restrict__ x, const float* __restrict__ g,
               const float* __restrict__ b, u16* __restrict__ out)
{
    __shared__ float red[4];
    const int row = blockIdx.x;
    const int t = threadIdx.x;
    const int wid = t >> 6, lane = t & 63;

    float4 v = *(const float4*)&x[(size_t)row * DIM + t * 4];
    float s  = v.x + v.y + v.z + v.w;
    float sq = v.x*v.x + v.y*v.y + v.z*v.z + v.w*v.w;
#pragma unroll
    for (int off = 32; off >= 1; off >>= 1) {
        s  += __shfl_xor(s, off);
        sq += __shfl_xor(sq, off);
    }
    if (lane == 0) { red[wid] = s; red[2 + wid] = sq; }
    __syncthreads();
    s = red[0] + red[1]; sq = red[2] + red[3];

    const float mu = s * (1.0f / DIM);
    const float rs = rsqrtf(sq * (1.0f / DIM) - mu * mu + LN_EPS);
    float4 gv = *(const float4*)&g[t * 4];
    float4 bv = *(const float4*)&b[t * 4];
    float ox = (v.x - mu) * rs * gv.x + bv.x;
    float oy = (v.y - mu) * rs * gv.y + bv.y;
    float oz = (v.z - mu) * rs * gv.z + bv.z;
    float ow = (v.w - mu) * rs * gv.w + bv.w;
    unsigned lo = f2bf(ox) | ((unsigned)f2bf(oy) << 16);
    unsigned hi = f2bf(oz) | ((unsigned)f2bf(ow) << 16);
    *(uint2*)&out[(size_t)row * DIM + t * 4] = make_uint2(lo, hi);
}

// Double LayerNorm: out = LN(LN(x,g1,b1),g2,b2), bf16 out.
__global__ __launch_bounds__(128)
void ln2_kernel(const float* __restrict__ x,
                const float* __restrict__ g1, const float* __restrict__ b1,
                const float* __restrict__ g2, const float* __restrict__ b2,
                u16* __restrict__ out)
{
    __shared__ float red[4];
    const int row = blockIdx.x;
    const int t = threadIdx.x;
    const int wid = t >> 6, lane = t & 63;

    float4 v = *(const float4*)&x[(size_t)row * DIM + t * 4];
    float s  = v.x + v.y + v.z + v.w;
    float sq = v.x*v.x + v.y*v.y + v.z*v.z + v.w*v.w;
#pragma unroll
    for (int off = 32; off >= 1; off >>= 1) {
        s  += __shfl_xor(s, off);
        sq += __shfl_xor(sq, off);
    }
    if (lane == 0) { red[wid] = s; red[2 + wid] = sq; }
    __syncthreads();
    s = red[0] + red[1]; sq = red[2] + red[3];
    float mu = s * (1.0f / DIM);
    float rs = rsqrtf(sq * (1.0f / DIM) - mu * mu + LN_EPS);

    float4 g = *(const float4*)&g1[t * 4];
    float4 bb = *(const float4*)&b1[t * 4];
    float4 z;
    z.x = (v.x - mu) * rs * g.x + bb.x;
    z.y = (v.y - mu) * rs * g.y + bb.y;
    z.z = (v.z - mu) * rs * g.z + bb.z;
    z.w = (v.w - mu) * rs * g.w + bb.w;

    s  = z.x + z.y + z.z + z.w;
    sq = z.x*z.x + z.y*z.y + z.z*z.z + z.w*z.w;
#pragma unroll
    for (int off = 32; off >= 1; off >>= 1) {
        s  += __shfl_xor(s, off);
        sq += __shfl_xor(sq, off);
    }
    __syncthreads();
    if (lane == 0) { red[wid] = s; red[2 + wid] = sq; }
    __syncthreads();
    s = red[0] + red[1]; sq = red[2] + red[3];
    mu = s * (1.0f / DIM);
    rs = rsqrtf(sq * (1.0f / DIM) - mu * mu + LN_EPS);

    g  = *(const float4*)&g2[t * 4];
    bb = *(const float4*)&b2[t * 4];
    float ox = (z.x - mu) * rs * g.x + bb.x;
    float oy = (z.y - mu) * rs * g.y + bb.y;
    float oz = (z.z - mu) * rs * g.z + bb.z;
    float ow = (z.w - mu) * rs * g.w + bb.w;
    unsigned lo = f2bf(ox) | ((unsigned)f2bf(oy) << 16);
    unsigned hi = f2bf(oz) | ((unsigned)f2bf(ow) << 16);
    *(uint2*)&out[(size_t)row * DIM + t * 4] = make_uint2(lo, hi);
}

// ---------------------------------------------------------------------------
// bf16 MFMA GEMM: C[M][Nc] = A[M][K] @ BT[Nc][K]^T  (+bias)(+gelu)(+res)
// BM=128, BN = NB*64 (NB=1 for narrow outputs -> 2 blocks/CU; NB=2 wide).
// BK=32, 4 waves (2x2), wave sub-tile 64 x (BN/2): 4 x 2*NB frags of
// 16x16x32 MFMA, fp32 accumulation.
// EPI: 0=bf16 out, 2=bias+res fp32 out, 3=bias+gelu bf16 out.
// ---------------------------------------------------------------------------
template<int EPI, int NB>
__global__ __launch_bounds__(256)
void gemm_bf16(const u16* __restrict__ A, const u16* __restrict__ BT,
               const float* __restrict__ bias, const float* __restrict__ res,
               void* __restrict__ Cv, int M, int K, int Nc)
{
    constexpr int BN = NB * 64;
    constexpr int NF = NB * 2;                  // n-frags per wave
    __shared__ __align__(16) u16 As[128][40];   // pad 8 bf16 -> 80B stride
    __shared__ __align__(16) u16 Bs[BN][40];

    const int t    = threadIdx.x;
    const int lane = t & 63;
    const int w    = t >> 6;
    const int wr   = (w >> 1) * 64, wc = (w & 1) * (BN / 2);
    const int rlo  = lane & 15, rhi = lane >> 4;
    const int row0 = blockIdx.y * 128, col0 = blockIdx.x * BN;

    const f32x4 z4 = {0.f, 0.f, 0.f, 0.f};
    f32x4 acc[4][NF];
#pragma unroll
    for (int m = 0; m < 4; ++m)
#pragma unroll
        for (int n = 0; n < NF; ++n) acc[m][n] = z4;

    uint4 pa[2], pb[NB];
    const int nkt = K >> 5;

#define LOADG(kt)                                                            \
    {                                                                        \
        _Pragma("unroll")                                                    \
        for (int i = 0; i < 2; ++i) {                                        \
            int idx = i * 256 + t, r = idx >> 2, c = idx & 3;                \
            pa[i] = *(const uint4*)&A[(size_t)(row0 + r) * K + (kt)*32 + c*8];\
        }                                                                    \
        _Pragma("unroll")                                                    \
        for (int i = 0; i < NB; ++i) {                                       \
            int idx = i * 256 + t, r = idx >> 2, c = idx & 3;                \
            pb[i] = *(const uint4*)&BT[(size_t)(col0 + r) * K + (kt)*32 + c*8];\
        }                                                                    \
    }

    LOADG(0);
    for (int kt = 0; kt < nkt; ++kt) {
        __syncthreads();
#pragma unroll
        for (int i = 0; i < 2; ++i) {
            int idx = i * 256 + t, r = idx >> 2, c = idx & 3;
            *(uint4*)&As[r][c * 8] = pa[i];
        }
#pragma unroll
        for (int i = 0; i < NB; ++i) {
            int idx = i * 256 + t, r = idx >> 2, c = idx & 3;
            *(uint4*)&Bs[r][c * 8] = pb[i];
        }
        __syncthreads();
        if (kt + 1 < nkt) LOADG(kt + 1);

        bf16x8 af[4], bf[NF];
#pragma unroll
        for (int m = 0; m < 4; ++m)
            af[m] = *(const bf16x8*)&As[wr + m * 16 + rlo][rhi * 8];
#pragma unroll
        for (int n = 0; n < NF; ++n)
            bf[n] = *(const bf16x8*)&Bs[wc + n * 16 + rlo][rhi * 8];
#pragma unroll
        for (int m = 0; m < 4; ++m)
#pragma unroll
            for (int n = 0; n < NF; ++n)
                acc[m][n] = __builtin_amdgcn_mfma_f32_16x16x32_bf16(
                    af[m], bf[n], acc[m][n], 0, 0, 0);
    }
#undef LOADG

    float* Cf = (float*)Cv;
    u16*   Cb = (u16*)Cv;
#pragma unroll
    for (int m = 0; m < 4; ++m) {
#pragma unroll
        for (int n = 0; n < NF; ++n) {
            const int cg = col0 + wc + n * 16 + rlo;
            const float bv = (EPI >= 2) ? bias[cg] : 0.0f;
#pragma unroll
            for (int i = 0; i < 4; ++i) {
                const size_t rg = (size_t)(row0 + wr + m * 16 + rhi * 4 + i);
                float val = acc[m][n][i] + bv;
                if (EPI == 3) val = gelu_f(val);
                if (EPI == 2) {
                    val += res[rg * Nc + cg];
                    Cf[rg * Nc + cg] = val;
                } else {
                    Cb[rg * Nc + cg] = f2bf(val);
                }
            }
        }
    }
}

// ---------------------------------------------------------------------------
// bf16 MFMA flash attention v2 — 32x32 swapped-operand form (round 8,
// measured good: dropped self-attn 152 -> <94 us). Unchanged.
// ---------------------------------------------------------------------------
__global__ __launch_bounds__(256)
void attn_mfma2(const u16* __restrict__ Q, int qs,
                const u16* __restrict__ K, const u16* __restrict__ V, int kvs,
                u16* __restrict__ O, int n_q, int n_k)
{
    __shared__ __align__(16) u16 Ks[64][72];
    __shared__ __align__(16) u16 VT[64][72];   // [d][kv ^ ((d>>3)<<3)]

    const int t    = threadIdx.x;
    const int lane = t & 63;
    const int w    = t >> 6;          // wave id: q rows [w*32, w*32+32)
    const int ql   = lane & 31;
    const int hi   = lane >> 5;
    const int bh = blockIdx.y, b = bh >> 3, h = bh & 7;
    const int q0 = blockIdx.x * 128;

    const u16* Qb = Q + (size_t)b * n_q * qs + h * DHEAD;
    const u16* Kb = K + (size_t)b * n_k * kvs + h * DHEAD;
    const u16* Vb = V + (size_t)b * n_k * kvs + h * DHEAD;

    // Q fragments (B operand, row=lane&31=q, k=hi*8+j), pre-scaled.
    const float QSC = ATT_SCALE * 1.44269504088896f;   // scale * log2(e)
    bf16x8 qf[4];
    {
        const u16* Qrow = Qb + (size_t)(q0 + w * 32 + ql) * qs;
#pragma unroll
        for (int kb = 0; kb < 4; ++kb) {
            uint4 raw = *(const uint4*)&Qrow[kb * 16 + hi * 8];
            u16 e[8]; *(uint4*)e = raw;
            union { unsigned u[4]; bf16x8 v; } uq;
#pragma unroll
            for (int j = 0; j < 4; ++j) {
                float lo = __uint_as_float((unsigned)e[2*j]     << 16) * QSC;
                float hf = __uint_as_float((unsigned)e[2*j + 1] << 16) * QSC;
                uq.u[j] = cvtpk_bf16(lo, hf);
            }
            qf[kb] = uq.v;
        }
    }

    const f32x16 z16 = {0.f,0.f,0.f,0.f,0.f,0.f,0.f,0.f,
                        0.f,0.f,0.f,0.f,0.f,0.f,0.f,0.f};
    f32x16 oa0 = z16, oa1 = z16;      // O[q=ql][d]: d = (r&3)+8*(r>>2)+4*hi (+32)
    float m = -1e30f, l = 0.f;

    const int ntiles = n_k >> 6;
    for (int it = 0; it < ntiles; ++it) {
        __syncthreads();   // prev tile consumed
#pragma unroll
        for (int i = 0; i < 2; ++i) {
            int idx = i * 256 + t, r = idx >> 3, c = idx & 7;
            *(uint4*)&Ks[r][c * 8] =
                *(const uint4*)&Kb[(size_t)(it * 64 + r) * kvs + c * 8];
            uint4 vv = *(const uint4*)&Vb[(size_t)(it * 64 + r) * kvs + c * 8];
            u16 e[8]; *(uint4*)e = vv;
            const int kvw = r ^ ((c & 7) << 3);
#pragma unroll
            for (int q = 0; q < 8; ++q)
                VT[c * 8 + q][kvw] = e[q];
        }
        __syncthreads();

        // S' = (Q*scale*log2e) @ K^T via mfma(K, Q); two 32-kv subtiles
        f32x16 s0 = z16, s1 = z16;
#pragma unroll
        for (int kb = 0; kb < 4; ++kb) {
            bf16x8 a0 = *(const bf16x8*)&Ks[ql]     [kb * 16 + hi * 8];
            bf16x8 a1 = *(const bf16x8*)&Ks[32 + ql][kb * 16 + hi * 8];
            s0 = __builtin_amdgcn_mfma_f32_32x32x16_bf16(a0, qf[kb], s0, 0, 0, 0);
            s1 = __builtin_amdgcn_mfma_f32_32x32x16_bf16(a1, qf[kb], s1, 0, 0, 0);
        }

        // row-max over this tile (in-register tree + one half-swap)
        float a[16];
#pragma unroll
        for (int i = 0; i < 16; ++i) a[i] = fmaxf(s0[i], s1[i]);
#pragma unroll
        for (int i = 0; i < 8; ++i) a[i] = fmaxf(a[i], a[i + 8]);
#pragma unroll
        for (int i = 0; i < 4; ++i) a[i] = fmaxf(a[i], a[i + 4]);
        a[0] = fmaxf(a[0], a[2]); a[1] = fmaxf(a[1], a[3]);
        a[0] = fmaxf(a[0], a[1]);
        float pmax = fmaxf(a[0], __shfl_xor(a[0], 32));

        // defer-max: skip rescale while tile max is within 5 (log2) of m
        if (!__all(pmax - m <= 5.0f)) {
            float mn = fmaxf(m, pmax);
            float al = __builtin_amdgcn_exp2f(m - mn);
            l *= al; oa0 *= al; oa1 *= al;
            m = mn;
        }

        f32x16 pe0, pe1;
        float sc[16];
#pragma unroll
        for (int i = 0; i < 16; ++i) {
            pe0[i] = __builtin_amdgcn_exp2f(s0[i] - m);
            pe1[i] = __builtin_amdgcn_exp2f(s1[i] - m);
            sc[i]  = pe0[i] + pe1[i];
        }
#pragma unroll
        for (int i = 0; i < 8; ++i) sc[i] += sc[i + 8];
#pragma unroll
        for (int i = 0; i < 4; ++i) sc[i] += sc[i + 4];
        float rsum = (sc[0] + sc[1]) + (sc[2] + sc[3]);
        rsum += __shfl_xor(rsum, 32);
        l += rsum;

        // PV: O += mfma(V^T, P) per 16-kv window. P frag built in-register:
        // X'=[X.lo|Y.lo] (words 0,1), Y'=[X.hi|Y.hi] (words 4,5) per swap.
#define PV_STEP(PE, KB2)                                                     \
        {                                                                    \
            const int w2 = ((KB2) & 1) * 8;                                  \
            unsigned Xw = cvtpk_bf16(PE[w2 + 0], PE[w2 + 1]);                \
            unsigned Zw = cvtpk_bf16(PE[w2 + 2], PE[w2 + 3]);                \
            unsigned Yw = cvtpk_bf16(PE[w2 + 4], PE[w2 + 5]);                \
            unsigned Ww = cvtpk_bf16(PE[w2 + 6], PE[w2 + 7]);                \
            asm volatile("v_permlane32_swap_b32 %0, %1"                      \
                         : "+v"(Yw), "+v"(Xw));                              \
            asm volatile("v_permlane32_swap_b32 %0, %1"                      \
                         : "+v"(Ww), "+v"(Zw));                              \
            union { unsigned u[4]; bf16x8 v; } pa_;                          \
            pa_.u[0] = Xw; pa_.u[1] = Zw; pa_.u[2] = Yw; pa_.u[3] = Ww;      \
            {                                                                \
                const int d0 = ql;                                           \
                const int c0 = ((KB2) * 16 + hi * 8) ^ (((d0 >> 3) & 7) << 3);\
                bf16x8 vb = *(const bf16x8*)&VT[d0][c0];                     \
                oa0 = __builtin_amdgcn_mfma_f32_32x32x16_bf16(vb, pa_.v, oa0, 0, 0, 0); \
            }                                                                \
            {                                                                \
                const int d1 = 32 + ql;                                      \
                const int c1 = ((KB2) * 16 + hi * 8) ^ (((d1 >> 3) & 7) << 3);\
                bf16x8 vb = *(const bf16x8*)&VT[d1][c1];                     \
                oa1 = __builtin_amdgcn_mfma_f32_32x32x16_bf16(vb, pa_.v, oa1, 0, 0, 0); \
            }                                                                \
        }
        PV_STEP(pe0, 0)
        PV_STEP(pe0, 1)
        PV_STEP(pe1, 2)
        PV_STEP(pe1, 3)
#undef PV_STEP
    }

    // epilogue: O[q][d] — lane owns row q=ql; d = 8g+4hi+i (+32 for oa1)
    const float inv = 1.0f / l;
    const size_t orow = (size_t)b * n_q + q0 + w * 32 + ql;
    u16* Op = O + orow * DIM + h * DHEAD;
#pragma unroll
    for (int g = 0; g < 4; ++g) {
        const int dbase = 8 * g + 4 * hi;
        unsigned w0 = cvtpk_bf16(oa0[4*g + 0] * inv, oa0[4*g + 1] * inv);
        unsigned w1 = cvtpk_bf16(oa0[4*g + 2] * inv, oa0[4*g + 3] * inv);
        *(uint2*)&Op[dbase] = make_uint2(w0, w1);
        unsigned w2 = cvtpk_bf16(oa1[4*g + 0] * inv, oa1[4*g + 1] * inv);
        unsigned w3 = cvtpk_bf16(oa1[4*g + 2] * inv, oa1[4*g + 3] * inv);
        *(uint2*)&Op[32 + dbase] = make_uint2(w2, w3);
    }
}

// ---------------------------------------------------------------------------
extern "C" void kernel_launch(void* const* d_in, const int* in_sizes, int n_in,
                              void* d_out, int out_size, void* d_ws, size_t ws_size,
                              hipStream_t stream)
{
    const float* x       = (const float*)d_in[0];
    const float* y       = (const float*)d_in[1];
    const float* sa_g    = (const float*)d_in[2];
    const float* sa_b    = (const float*)d_in[3];
    const float* sa_wqkv = (const float*)d_in[4];
    const float* sa_wo   = (const float*)d_in[5];
    const float* sa_bo   = (const float*)d_in[6];
    const float* n1_g    = (const float*)d_in[7];
    const float* n1_b    = (const float*)d_in[8];
    const float* ca_g    = (const float*)d_in[9];
    const float* ca_b    = (const float*)d_in[10];
    const float* ca_wq   = (const float*)d_in[11];
    const float* ca_wkv  = (const float*)d_in[12];
    const float* ca_wo   = (const float*)d_in[13];
    const float* ca_bo   = (const float*)d_in[14];
    const float* ff_g    = (const float*)d_in[15];
    const float* ff_b    = (const float*)d_in[16];
    const float* ff_w1   = (const float*)d_in[17];
    const float* ff_b1   = (const float*)d_in[18];
    const float* ff_w2   = (const float*)d_in[19];
    const float* ff_b2   = (const float*)d_in[20];
    float* out = (float*)d_out;

    const int Mx = BATCH * NQ;    // 8192
    const int My = BATCH * NKV;   // 4096

    // workspace (bf16/u16 units), total 39,845,888 u16 = 76 MiB
    u16* xb    = (u16*)d_ws;            // 4,194,304  (LN output)
    u16* bigb  = xb    + 4194304;       // 16,777,216 (qkv 12.6M / ff hidden 16.8M)
    u16* attb  = bigb  + 16777216;      // 4,194,304  (attention output)
    u16* q2b   = attb  + 4194304;       // 4,194,304
    u16* kvb   = q2b   + 4194304;       // 4,194,304
    u16* ybb   = kvb   + 4194304;       // 2,097,152
    u16* wqkvT = ybb   + 2097152;       // 786,432
    u16* woT   = wqkvT + 786432;        // 262,144
    u16* caqT  = woT   + 262144;        // 262,144
    u16* cakvT = caqT  + 262144;        // 524,288
    u16* caoT  = cakvT + 524288;        // 262,144
    u16* w1T   = caoT  + 262144;        // 1,048,576
    u16* w2T   = w1T   + 1048576;       // 1,048,576

    // --- prep: convert y, transpose+convert weights ---
    f2b_kernel<<<(My * DIM / 4 + 255) / 256, 256, 0, stream>>>(y, ybb, My * DIM / 4);
    wtrans_kernel<<<dim3(1536 / 32, 512 / 32),  256, 0, stream>>>(sa_wqkv, wqkvT, 512, 1536);
    wtrans_kernel<<<dim3(512 / 32,  512 / 32),  256, 0, stream>>>(sa_wo,   woT,   512, 512);
    wtrans_kernel<<<dim3(512 / 32,  512 / 32),  256, 0, stream>>>(ca_wq,   caqT,  512, 512);
    wtrans_kernel<<<dim3(1024 / 32, 512 / 32),  256, 0, stream>>>(ca_wkv,  cakvT, 512, 1024);
    wtrans_kernel<<<dim3(512 / 32,  512 / 32),  256, 0, stream>>>(ca_wo,   caoT,  512, 512);
    wtrans_kernel<<<dim3(2048 / 32, 512 / 32),  256, 0, stream>>>(ff_w1,   w1T,   512, 2048);
    wtrans_kernel<<<dim3(512 / 32,  2048 / 32), 256, 0, stream>>>(ff_w2,   w2T,   2048, 512);

    // --- self-attention ---
    ln_kernel<<<Mx, 128, 0, stream>>>(x, sa_g, sa_b, xb);
    gemm_bf16<0, 2><<<dim3(1536 / 128, Mx / 128), 256, 0, stream>>>(
        xb, wqkvT, nullptr, nullptr, bigb, Mx, 512, 1536);
    attn_mfma2<<<dim3(NQ / 128, BATCH * HEADS), 256, 0, stream>>>(
        bigb, 1536, bigb + 512, bigb + 1024, 1536, attb, NQ, NQ);
    gemm_bf16<2, 1><<<dim3(512 / 64, Mx / 128), 256, 0, stream>>>(
        attb, woT, sa_bo, x, out, Mx, 512, 512);

    // --- cross-attention ---
    ln2_kernel<<<Mx, 128, 0, stream>>>(out, n1_g, n1_b, ca_g, ca_b, xb);
    gemm_bf16<0, 1><<<dim3(512 / 64, Mx / 128), 256, 0, stream>>>(
        xb, caqT, nullptr, nullptr, q2b, Mx, 512, 512);
    gemm_bf16<0, 1><<<dim3(1024 / 64, My / 128), 256, 0, stream>>>(
        ybb, cakvT, nullptr, nullptr, kvb, My, 512, 1024);
    attn_mfma2<<<dim3(NQ / 128, BATCH * HEADS), 256, 0, stream>>>(
        q2b, 512, kvb, kvb + 512, 1024, attb, NQ, NKV);
    gemm_bf16<2, 1><<<dim3(512 / 64, Mx / 128), 256, 0, stream>>>(
        attb, caoT, ca_bo, out, out, Mx, 512, 512);

    // --- MLP ---
    ln_kernel<<<Mx, 128, 0, stream>>>(out, ff_g, ff_b, xb);
    gemm_bf16<3, 2><<<dim3(2048 / 128, Mx / 128), 256, 0, stream>>>(
        xb, w1T, ff_b1, nullptr, bigb, Mx, 512, 2048);
    gemm_bf16<2, 1><<<dim3(512 / 64, Mx / 128), 256, 0, stream>>>(
        bigb, w2T, ff_b2, out, out, Mx, 2048, 512);

    (void)in_sizes; (void)n_in; (void)out_size; (void)ws_size;
}